// Round 4
// baseline (370.232 us; speedup 1.0000x reference)
//
#include <hip/hip_runtime.h>
#include <math.h>

#define HID 256
#define EMB 64
#define KTOT 320            // HID + EMB
#define MT 32               // words per block
#define NBLK 256
#define THREADS 1024        // 16 waves = 4 waves/SIMD (pinned)
#define KT 10               // k-tiles of 32
#define XSTR 328            // Xs row stride (f16): 656B -> 16B aligned

typedef _Float16 f16;
typedef _Float16 f16x2 __attribute__((ext_vector_type(2)));
typedef _Float16 f16x8 __attribute__((ext_vector_type(8)));
typedef float f32x4 __attribute__((ext_vector_type(4)));

__device__ __forceinline__ float sigm(float x) { return 1.0f / (1.0f + __expf(-x)); }

// LDS-only barrier: drain LDS ops, keep global loads in flight across it.
__device__ __forceinline__ void bar_lds() {
  asm volatile("s_waitcnt lgkmcnt(0)" ::: "memory");
  __builtin_amdgcn_sched_barrier(0);
  __builtin_amdgcn_s_barrier();
  __builtin_amdgcn_sched_barrier(0);
}

// Column packing: gate row g = q*256 + u  ->  col = (u>>4)*64 + q*16 + (u&15).
// Wave wv owns cols [wv*64, wv*64+64): all 4 gates of units [wv*16, wv*16+16).
// Wfrag[(kt*1024 + col)*32 + (k&31)] = f16(Wcat[g][k]), Wcat[g] = [W_hh | W_ih].
__global__ __launch_bounds__(KTOT) void prep_w(const float* __restrict__ W_ih,
                                               const float* __restrict__ W_hh,
                                               const float* __restrict__ b_ih,
                                               const float* __restrict__ b_hh,
                                               f16* __restrict__ Wfrag,
                                               float* __restrict__ bias_p) {
  const int g = blockIdx.x;           // 0..1023
  const int k = threadIdx.x;          // 0..319
  const int q = g >> 8, u = g & 255;
  const int col = ((u >> 4) << 6) + (q << 4) + (u & 15);
  const float w = (k < HID) ? W_hh[g * HID + k] : W_ih[g * EMB + (k - HID)];
  const int kt = k >> 5;
  Wfrag[((size_t)(kt * 1024 + col)) * 32 + (k & 31)] = (f16)w;
  if (k == 0) bias_p[col] = b_ih[g] + b_hh[g];
}

__global__ __launch_bounds__(THREADS)
__attribute__((amdgpu_waves_per_eu(4, 4)))      // pin 4 waves/SIMD -> 128 VGPR budget, no spill
void lstm_mfma(
    const int* __restrict__ chars, const int* __restrict__ wordlens,
    const int* __restrict__ orig_idx, const float* __restrict__ emb_table,
    const float* __restrict__ attn_w, const float* __restrict__ h_init,
    const float* __restrict__ c_init, const f16* __restrict__ Wfrag,
    const float* __restrict__ bias_p, float* __restrict__ out) {
  __shared__ __align__(16) f16 Xs[MT * XSTR];   // [m][k]: k<256 = h_{t-1}, k>=256 = x_t
  __shared__ float attP[16 * MT];               // [wave][word] attention partials
  __shared__ float wgt_s[MT];
  __shared__ int   chars_s[MT * 16];
  __shared__ int   len_s[MT];
  __shared__ int   oidx_s[MT];

  const int tid  = threadIdx.x;
  const int w0   = blockIdx.x * MT;
  const int lane = tid & 63;
  const int wv   = tid >> 6;          // 0..15, owns cols [wv*64, wv*64+64)
  const int r15  = lane & 15, c4 = lane >> 4;
  const int n0   = wv * 64;
  const int u    = wv * 16 + r15;     // unit owned in cell phase

  if (tid < MT * 16) chars_s[tid] = chars[w0 * 16 + tid];
  if (tid < MT) { len_s[tid] = wordlens[w0 + tid]; oidx_s[tid] = orig_idx[w0 + tid]; }

  // init Xs h-region with h_init
  {
    const int j = tid & 255, mb = tid >> 8;
    const f16 hv = (f16)h_init[j];
#pragma unroll
    for (int mm = 0; mm < 8; ++mm) Xs[(mb + mm * 4) * XSTR + j] = hv;
  }
  // stage x_0 (read chars straight from global; chars_s not yet visible)
  {
    const int m = tid >> 5, e2 = tid & 31;
    const int ch_g = chars[(w0 + m) * 16 + 0];
    const float2 e = ((const float2*)emb_table)[ch_g * 32 + e2];
    f16x2 ev = { (f16)e.x, (f16)e.y };
    *(f16x2*)&Xs[m * XSTR + HID + e2 * 2] = ev;
  }

  const float aw = attn_w[u];
  float biasr[4];
#pragma unroll
  for (int q = 0; q < 4; ++q) biasr[q] = bias_p[n0 + q * 16 + r15];

  float c_reg[8], res[8], h_new[8];
  {
    const float cini = c_init[u];
#pragma unroll
    for (int i = 0; i < 8; ++i) { c_reg[i] = cini; res[i] = 0.0f; h_new[i] = 0.0f; }
  }

  __syncthreads();   // full barrier once after init

  int steps = 1;
#pragma unroll
  for (int m = 0; m < MT; ++m) steps = max(steps, len_s[m]);

  const size_t bofs = (size_t)(n0 + r15) * 4 + c4;  // in f16x8 units; +q*64 per gate

  for (int t = 0; t < steps; ++t) {
    f32x4 acc[4][2];
#pragma unroll
    for (int q = 0; q < 4; ++q) {
      const f32x4 b4 = { biasr[q], biasr[q], biasr[q], biasr[q] };
      acc[q][0] = b4; acc[q][1] = b4;
    }

#pragma unroll
    for (int kt = 0; kt < KT; ++kt) {
      const f16x8* __restrict__ Wp = ((const f16x8*)Wfrag) + (size_t)kt * 4096;
      f16x8 bc[4];
#pragma unroll
      for (int q = 0; q < 4; ++q) bc[q] = Wp[bofs + (size_t)q * 64];

      const f16x8 a0 = *(const f16x8*)&Xs[r15 * XSTR + kt * 32 + c4 * 8];
      const f16x8 a1 = *(const f16x8*)&Xs[(16 + r15) * XSTR + kt * 32 + c4 * 8];
#pragma unroll
      for (int q = 0; q < 4; ++q) {
        acc[q][0] = __builtin_amdgcn_mfma_f32_16x16x32_f16(a0, bc[q], acc[q][0], 0, 0, 0);
        acc[q][1] = __builtin_amdgcn_mfma_f32_16x16x32_f16(a1, bc[q], acc[q][1], 0, 0, 0);
      }
    }

    // ---- LSTM cell, fully in registers (lane: unit u, words mt*16 + c4*4 + r)
#pragma unroll
    for (int mt = 0; mt < 2; ++mt) {
#pragma unroll
      for (int r = 0; r < 4; ++r) {
        const int idx = mt * 4 + r;
        const float gi = acc[0][mt][r];
        const float gf = acc[1][mt][r];
        const float gg = acc[2][mt][r];
        const float go = acc[3][mt][r];
        const float cc = sigm(gf) * c_reg[idx] + sigm(gi) * tanhf(gg);
        c_reg[idx] = cc;
        h_new[idx] = sigm(go) * tanhf(cc);
      }
    }

    bar_lds();  // all A-reads of this step complete; Xs/attP writable

    // write h_t -> Xs, stage x_{t+1}
    if (t + 1 < steps) {
#pragma unroll
      for (int mt = 0; mt < 2; ++mt)
#pragma unroll
        for (int r = 0; r < 4; ++r)
          Xs[(mt * 16 + c4 * 4 + r) * XSTR + u] = (f16)h_new[mt * 4 + r];
      {
        const int m = tid >> 5, e2 = tid & 31;
        const int ch = chars_s[m * 16 + (t + 1)];
        const float2 e = ((const float2*)emb_table)[ch * 32 + e2];
        f16x2 ev = { (f16)e.x, (f16)e.y };
        *(f16x2*)&Xs[m * XSTR + HID + e2 * 2] = ev;
      }
    }

    // attention partials: reduce over r15 group (16 units per wave)
#pragma unroll
    for (int mt = 0; mt < 2; ++mt) {
#pragma unroll
      for (int r = 0; r < 4; ++r) {
        const int idx = mt * 4 + r;
        float p = h_new[idx] * aw;
        p += __shfl_xor(p, 1); p += __shfl_xor(p, 2);
        p += __shfl_xor(p, 4); p += __shfl_xor(p, 8);
        if (r15 == 0) attP[wv * MT + mt * 16 + c4 * 4 + r] = p;
      }
    }

    bar_lds();

    if (tid < MT) {
      float s = 0.0f;
#pragma unroll
      for (int w = 0; w < 16; ++w) s += attP[w * MT + tid];
      wgt_s[tid] = (t < len_s[tid]) ? sigm(s) : 0.0f;
    }

    bar_lds();

#pragma unroll
    for (int mt = 0; mt < 2; ++mt)
#pragma unroll
      for (int r = 0; r < 4; ++r) {
        const int idx = mt * 4 + r;
        res[idx] += wgt_s[mt * 16 + c4 * 4 + r] * h_new[idx];
      }
  }

  // ---- tensor_unsort + write: lane stores unit u for its 8 words
#pragma unroll
  for (int mt = 0; mt < 2; ++mt)
#pragma unroll
    for (int r = 0; r < 4; ++r) {
      const int m = mt * 16 + c4 * 4 + r;
      out[(size_t)oidx_s[m] * HID + u] = res[mt * 4 + r];
    }
}

extern "C" void kernel_launch(void* const* d_in, const int* in_sizes, int n_in,
                              void* d_out, int out_size, void* d_ws, size_t ws_size,
                              hipStream_t stream) {
  const int*   chars    = (const int*)d_in[0];
  const int*   wordlens = (const int*)d_in[1];
  const int*   orig_idx = (const int*)d_in[2];
  const float* emb      = (const float*)d_in[3];
  const float* W_ih     = (const float*)d_in[4];
  const float* W_hh     = (const float*)d_in[5];
  const float* b_ih     = (const float*)d_in[6];
  const float* b_hh     = (const float*)d_in[7];
  const float* attn_w   = (const float*)d_in[8];
  const float* h_init   = (const float*)d_in[9];
  const float* c_init   = (const float*)d_in[10];
  float* out = (float*)d_out;

  f16*   Wfrag  = (f16*)d_ws;                      // 320*1024 f16 = 640 KiB
  float* bias_p = (float*)((char*)d_ws + (size_t)KTOT * 1024 * sizeof(f16));
  if (ws_size < (size_t)KTOT * 1024 * sizeof(f16) + 1024 * sizeof(float)) return;

  hipLaunchKernelGGL(prep_w, dim3(1024), dim3(KTOT), 0, stream,
                     W_ih, W_hh, b_ih, b_hh, Wfrag, bias_p);
  hipLaunchKernelGGL(lstm_mfma, dim3(NBLK), dim3(THREADS), 0, stream,
                     chars, wordlens, orig_idx, emb, attn_w, h_init, c_init,
                     Wfrag, bias_p, out);
}

// Round 5
// 253.203 us; speedup vs baseline: 1.4622x; 1.4622x over previous
//
#include <hip/hip_runtime.h>
#include <math.h>

#define HID 256
#define EMB 64
#define KTOT 320            // HID + EMB
#define MT 32               // words per block
#define NBLK 256            // 1 block per CU
#define THREADS 512         // 8 waves (proven allocator regime)
#define KT 10               // k-tiles of 32
#define XSTR 328            // Xs row stride (f16): 656B, 16B-aligned

typedef _Float16 f16;
typedef _Float16 f16x4 __attribute__((ext_vector_type(4)));
typedef _Float16 f16x8 __attribute__((ext_vector_type(8)));
typedef float f32x4 __attribute__((ext_vector_type(4)));

__device__ __forceinline__ float sigm(float x) { return 1.0f / (1.0f + __expf(-x)); }

// Column packing: gate row g = q*256 + u  ->  col = (u>>5)*128 + q*32 + ((u>>4)&1)*16 + (u&15).
// Wave wv owns cols [wv*128, wv*128+128) = all 4 gates of units [wv*32, wv*32+32).
// Wfrag[(kt*1024 + col)*32 + (k&31)] = f16(Wcat[g][k]), Wcat[g] = [W_hh | W_ih].
__global__ __launch_bounds__(KTOT) void prep_w(const float* __restrict__ W_ih,
                                               const float* __restrict__ W_hh,
                                               const float* __restrict__ b_ih,
                                               const float* __restrict__ b_hh,
                                               f16* __restrict__ Wfrag,
                                               float* __restrict__ bias_p) {
  const int g = blockIdx.x;           // 0..1023
  const int k = threadIdx.x;          // 0..319
  const int q = g >> 8, u = g & 255;
  const int col = ((u >> 5) << 7) + (q << 5) + (((u >> 4) & 1) << 4) + (u & 15);
  const float w = (k < HID) ? W_hh[g * HID + k] : W_ih[g * EMB + (k - HID)];
  const int kt = k >> 5;
  Wfrag[((size_t)(kt * 1024 + col)) * 32 + (k & 31)] = (f16)w;
  if (k == 0) bias_p[col] = b_ih[g] + b_hh[g];
}

__global__ __launch_bounds__(THREADS, 2) void lstm_mfma(
    const int* __restrict__ chars, const int* __restrict__ wordlens,
    const int* __restrict__ orig_idx, const float* __restrict__ emb_table,
    const float* __restrict__ attn_w, const float* __restrict__ h_init,
    const float* __restrict__ c_init, const f16* __restrict__ Wfrag,
    const float* __restrict__ bias_p, float* __restrict__ out) {
  __shared__ __align__(16) f16 Xs[MT * XSTR];   // [m][k]: k<256 = h_{t-1}, k>=256 = x_t
  __shared__ __align__(16) float attP[MT * 8];  // [word][wave] attention partials
  __shared__ int chars_s[MT * 16];
  __shared__ int len_s[MT];
  __shared__ int oidx_s[MT];

  const int tid  = threadIdx.x;
  const int w0   = blockIdx.x * MT;
  const int lane = tid & 63;
  const int wv   = tid >> 6;          // 0..7, owns cols [wv*128, wv*128+128)
  const int r15  = lane & 15, c4 = lane >> 4;
  const int u0   = wv * 32 + r15;     // unit owned (s=0); s=1 -> u0+16

  chars_s[tid] = chars[w0 * 16 + tid];
  if (tid < MT) { len_s[tid] = wordlens[w0 + tid]; oidx_s[tid] = orig_idx[w0 + tid]; }

  // init Xs h-region with h_init
  {
    const int j = tid & 255, mb = tid >> 8;
    const f16 hv = (f16)h_init[j];
#pragma unroll
    for (int mm = 0; mm < 16; ++mm) Xs[(mb + mm * 2) * XSTR + j] = hv;
  }
  // stage x_0 (chars from global; chars_s not yet visible)
  {
    const int m = tid >> 4, e4 = tid & 15;
    const int ch_g = chars[(w0 + m) * 16 + 0];
    const float4 e = ((const float4*)emb_table)[ch_g * 16 + e4];
    f16x4 ev = { (f16)e.x, (f16)e.y, (f16)e.z, (f16)e.w };
    *(f16x4*)&Xs[m * XSTR + HID + e4 * 4] = ev;
  }

  const float aw0 = attn_w[u0];
  const float aw1 = attn_w[u0 + 16];
  float biasr[4][2];
#pragma unroll
  for (int q = 0; q < 4; ++q) {
    biasr[q][0] = bias_p[wv * 128 + q * 32 + r15];
    biasr[q][1] = bias_p[wv * 128 + q * 32 + 16 + r15];
  }

  float c_reg[2][8], res[2][8], h_new[2][8];
  {
    const float c0 = c_init[u0], c1 = c_init[u0 + 16];
#pragma unroll
    for (int i = 0; i < 8; ++i) {
      c_reg[0][i] = c0; c_reg[1][i] = c1;
      res[0][i] = 0.0f; res[1][i] = 0.0f;
      h_new[0][i] = 0.0f; h_new[1][i] = 0.0f;
    }
  }

  __syncthreads();

  int steps = 1;
#pragma unroll
  for (int m = 0; m < MT; ++m) steps = max(steps, len_s[m]);
  int lenr[8];
#pragma unroll
  for (int mt = 0; mt < 2; ++mt)
#pragma unroll
    for (int r = 0; r < 4; ++r) lenr[mt * 4 + r] = len_s[mt * 16 + c4 * 4 + r];

  // B index (f16x8 units): (kt*1024 + wv*128 + q*32 + s*16 + r15)*4 + c4
  const size_t bofs = (size_t)(wv * 128 + r15) * 4 + c4;

  for (int t = 0; t < steps; ++t) {
    f32x4 acc[4][2][2];   // [gate q][unit-half s][m-tile mt]
#pragma unroll
    for (int q = 0; q < 4; ++q)
#pragma unroll
      for (int s = 0; s < 2; ++s) {
        const float b = biasr[q][s];
        const f32x4 b4 = { b, b, b, b };
        acc[q][s][0] = b4; acc[q][s][1] = b4;
      }

#pragma unroll 2
    for (int kt = 0; kt < KT; ++kt) {
      const f16x8* __restrict__ Wp = ((const f16x8*)Wfrag) + (size_t)kt * 4096;
      const f16x8 a0 = *(const f16x8*)&Xs[r15 * XSTR + kt * 32 + c4 * 8];
      const f16x8 a1 = *(const f16x8*)&Xs[(16 + r15) * XSTR + kt * 32 + c4 * 8];
#pragma unroll
      for (int q = 0; q < 4; ++q) {
#pragma unroll
        for (int s = 0; s < 2; ++s) {
          const f16x8 b = Wp[bofs + (size_t)(q * 32 + s * 16) * 4];
          acc[q][s][0] = __builtin_amdgcn_mfma_f32_16x16x32_f16(a0, b, acc[q][s][0], 0, 0, 0);
          acc[q][s][1] = __builtin_amdgcn_mfma_f32_16x16x32_f16(a1, b, acc[q][s][1], 0, 0, 0);
        }
      }
    }

    // ---- LSTM cell in registers: lane owns units u0,u0+16, words mt*16+c4*4+r
#pragma unroll
    for (int s = 0; s < 2; ++s)
#pragma unroll
      for (int mt = 0; mt < 2; ++mt)
#pragma unroll
        for (int r = 0; r < 4; ++r) {
          const int i = mt * 4 + r;
          const float gi = acc[0][s][mt][r];
          const float gf = acc[1][s][mt][r];
          const float gg = acc[2][s][mt][r];
          const float go = acc[3][s][mt][r];
          const float cc = sigm(gf) * c_reg[s][i] + sigm(gi) * tanhf(gg);
          c_reg[s][i] = cc;
          h_new[s][i] = sigm(go) * tanhf(cc);
        }

    __syncthreads();   // A-reads of this step done; Xs/attP writable

    // write h_t -> Xs; stage x_{t+1}
    if (t + 1 < steps) {
#pragma unroll
      for (int s = 0; s < 2; ++s)
#pragma unroll
        for (int mt = 0; mt < 2; ++mt)
#pragma unroll
          for (int r = 0; r < 4; ++r)
            Xs[(mt * 16 + c4 * 4 + r) * XSTR + u0 + s * 16] = (f16)h_new[s][mt * 4 + r];
      {
        const int m = tid >> 4, e4 = tid & 15;
        const int ch = chars_s[m * 16 + (t + 1)];
        const float4 e = ((const float4*)emb_table)[ch * 16 + e4];
        f16x4 ev = { (f16)e.x, (f16)e.y, (f16)e.z, (f16)e.w };
        *(f16x4*)&Xs[m * XSTR + HID + e4 * 4] = ev;
      }
    }

    // attention partials: this wave's 32 units, butterfly over r15 group
#pragma unroll
    for (int mt = 0; mt < 2; ++mt)
#pragma unroll
      for (int r = 0; r < 4; ++r) {
        const int i = mt * 4 + r;
        float p = h_new[0][i] * aw0 + h_new[1][i] * aw1;
        p += __shfl_xor(p, 1); p += __shfl_xor(p, 2);
        p += __shfl_xor(p, 4); p += __shfl_xor(p, 8);
        if (r15 == 0) attP[(mt * 16 + c4 * 4 + r) * 8 + wv] = p;
      }

    __syncthreads();

    // redundant per-lane weight: read 8 wave-partials (broadcast), sigm, mask, accumulate
#pragma unroll
    for (int mt = 0; mt < 2; ++mt)
#pragma unroll
      for (int r = 0; r < 4; ++r) {
        const int i = mt * 4 + r;
        const int w = mt * 16 + c4 * 4 + r;
        const f32x4 p0 = *(const f32x4*)&attP[w * 8];
        const f32x4 p1 = *(const f32x4*)&attP[w * 8 + 4];
        const float sum = (p0[0] + p0[1]) + (p0[2] + p0[3]) + (p1[0] + p1[1]) + (p1[2] + p1[3]);
        const float wgt = (t < lenr[i]) ? sigm(sum) : 0.0f;
        res[0][i] = fmaf(wgt, h_new[0][i], res[0][i]);
        res[1][i] = fmaf(wgt, h_new[1][i], res[1][i]);
      }
  }

  // ---- tensor_unsort + write
#pragma unroll
  for (int s = 0; s < 2; ++s)
#pragma unroll
    for (int mt = 0; mt < 2; ++mt)
#pragma unroll
      for (int r = 0; r < 4; ++r) {
        const int w = mt * 16 + c4 * 4 + r;
        out[(size_t)oidx_s[w] * HID + u0 + s * 16] = res[s][mt * 4 + r];
      }
}

extern "C" void kernel_launch(void* const* d_in, const int* in_sizes, int n_in,
                              void* d_out, int out_size, void* d_ws, size_t ws_size,
                              hipStream_t stream) {
  const int*   chars    = (const int*)d_in[0];
  const int*   wordlens = (const int*)d_in[1];
  const int*   orig_idx = (const int*)d_in[2];
  const float* emb      = (const float*)d_in[3];
  const float* W_ih     = (const float*)d_in[4];
  const float* W_hh     = (const float*)d_in[5];
  const float* b_ih     = (const float*)d_in[6];
  const float* b_hh     = (const float*)d_in[7];
  const float* attn_w   = (const float*)d_in[8];
  const float* h_init   = (const float*)d_in[9];
  const float* c_init   = (const float*)d_in[10];
  float* out = (float*)d_out;

  f16*   Wfrag  = (f16*)d_ws;                      // 320*1024 f16 = 640 KiB
  float* bias_p = (float*)((char*)d_ws + (size_t)KTOT * 1024 * sizeof(f16));
  if (ws_size < (size_t)KTOT * 1024 * sizeof(f16) + 1024 * sizeof(float)) return;

  hipLaunchKernelGGL(prep_w, dim3(1024), dim3(KTOT), 0, stream,
                     W_ih, W_hh, b_ih, b_hh, Wfrag, bias_p);
  hipLaunchKernelGGL(lstm_mfma, dim3(NBLK), dim3(THREADS), 0, stream,
                     chars, wordlens, orig_idx, emb, attn_w, h_init, c_init,
                     Wfrag, bias_p, out);
}